// Round 1
// baseline (2546.736 us; speedup 1.0000x reference)
//
#include <hip/hip_runtime.h>

#define DIM 128
#define EPS 1e-5f

__device__ __forceinline__ int lower_bound_i(const int* __restrict__ a, int n, int key) {
  int lo = 0, hi = n;
  while (lo < hi) {
    int mid = (lo + hi) >> 1;
    if (a[mid] < key) lo = mid + 1; else hi = mid;
  }
  return lo;
}

__global__ __launch_bounds__(256) void deg_kernel(const int* __restrict__ dst,
                                                  float* __restrict__ deg, int nE) {
  int i = blockIdx.x * 256 + threadIdx.x;
  if (i < nE) atomicAdd(&deg[dst[i]], 1.0f);
}

// One edge handled by 32 threads (4 floats each via float4 load + 4 scalar atomics).
__global__ __launch_bounds__(256) void scatter_kernel(const float* __restrict__ x,
    const int* __restrict__ src, const int* __restrict__ dst,
    float* __restrict__ agg, int nE) {
  int idx = blockIdx.x * 256 + threadIdx.x;
  int total = nE * 32;
  if (idx >= total) return;
  int e = idx >> 5, j = idx & 31;
  int s = src[e], d = dst[e];
  float4 v = reinterpret_cast<const float4*>(x)[(size_t)s * 32 + j];
  float* p = agg + (size_t)d * DIM + j * 4;
  atomicAdd(p + 0, v.x);
  atomicAdd(p + 1, v.y);
  atomicAdd(p + 2, v.z);
  atomicAdd(p + 3, v.w);
}

// h[n][c] = (agg[n][:]/deg[n]) @ Wl[:, c] + bias[c] + x[n][:] @ Wr[:, c]
// Block: 256 threads, 16 rows x 128 cols tile. Thread: (c4 = 4 cols, 2 rows).
__global__ __launch_bounds__(256) void gemm_kernel(const float* __restrict__ agg,
    const float* __restrict__ deg, const float* __restrict__ x,
    const float* __restrict__ Wl, const float* __restrict__ bias,
    const float* __restrict__ Wr, float* __restrict__ h, int nN) {
  __shared__ float a_sh[16][DIM];
  __shared__ float x_sh[16][DIM];
  const int tid = threadIdx.x;
  const int n0 = blockIdx.x * 16;
#pragma unroll
  for (int i = 0; i < 8; ++i) {
    int idx = tid + i * 256;
    int lr = idx >> 7, cc = idx & 127;
    int n = n0 + lr;
    if (n >= nN) n = nN - 1;
    float invd = 1.0f / fmaxf(deg[n], 1.0f);
    a_sh[lr][cc] = agg[(size_t)n * DIM + cc] * invd;
    x_sh[lr][cc] = x[(size_t)n * DIM + cc];
  }
  __syncthreads();
  const int c4 = (tid & 31) * 4;
  const int rg = tid >> 5;  // 0..7 -> rows rg and rg+8
  float acc0[4], acc1[4];
#pragma unroll
  for (int j = 0; j < 4; ++j) { acc0[j] = bias[c4 + j]; acc1[j] = acc0[j]; }
  for (int kb = 0; kb < DIM; kb += 4) {
    float4 a0 = *reinterpret_cast<const float4*>(&a_sh[rg][kb]);
    float4 a1 = *reinterpret_cast<const float4*>(&a_sh[rg + 8][kb]);
    float4 x0 = *reinterpret_cast<const float4*>(&x_sh[rg][kb]);
    float4 x1 = *reinterpret_cast<const float4*>(&x_sh[rg + 8][kb]);
    const float* a0p = reinterpret_cast<const float*>(&a0);
    const float* a1p = reinterpret_cast<const float*>(&a1);
    const float* x0p = reinterpret_cast<const float*>(&x0);
    const float* x1p = reinterpret_cast<const float*>(&x1);
#pragma unroll
    for (int kk = 0; kk < 4; ++kk) {
      float4 wl = *reinterpret_cast<const float4*>(&Wl[(size_t)(kb + kk) * DIM + c4]);
      float4 wr = *reinterpret_cast<const float4*>(&Wr[(size_t)(kb + kk) * DIM + c4]);
      float av0 = a0p[kk], av1 = a1p[kk];
      float xv0 = x0p[kk], xv1 = x1p[kk];
      acc0[0] += av0 * wl.x + xv0 * wr.x;
      acc0[1] += av0 * wl.y + xv0 * wr.y;
      acc0[2] += av0 * wl.z + xv0 * wr.z;
      acc0[3] += av0 * wl.w + xv0 * wr.w;
      acc1[0] += av1 * wl.x + xv1 * wr.x;
      acc1[1] += av1 * wl.y + xv1 * wr.y;
      acc1[2] += av1 * wl.z + xv1 * wr.z;
      acc1[3] += av1 * wl.w + xv1 * wr.w;
    }
  }
  int r0 = n0 + rg, r1 = n0 + rg + 8;
  if (r0 < nN) {
    float4 o = make_float4(acc0[0], acc0[1], acc0[2], acc0[3]);
    *reinterpret_cast<float4*>(&h[(size_t)r0 * DIM + c4]) = o;
  }
  if (r1 < nN) {
    float4 o = make_float4(acc1[0], acc1[1], acc1[2], acc1[3]);
    *reinterpret_cast<float4*>(&h[(size_t)r1 * DIM + c4]) = o;
  }
}

// Per-column sum and sum-of-squares over N rows.
__global__ __launch_bounds__(256) void stats_kernel(const float* __restrict__ h,
                                                    float* __restrict__ sums, int nN) {
  __shared__ float s_s[256];
  __shared__ float s_q[256];
  int tid = threadIdx.x;
  int c = tid & 127;
  int rp = tid >> 7;
  float ls = 0.f, lq = 0.f;
  for (int r = blockIdx.x * 2 + rp; r < nN; r += gridDim.x * 2) {
    float v = h[(size_t)r * DIM + c];
    ls += v;
    lq += v * v;
  }
  s_s[tid] = ls;
  s_q[tid] = lq;
  __syncthreads();
  if (tid < 128) {
    atomicAdd(&sums[c], s_s[tid] + s_s[tid + 128]);
    atomicAdd(&sums[DIM + c], s_q[tid] + s_q[tid + 128]);
  }
}

__global__ __launch_bounds__(256) void bn_relu_kernel(const float* __restrict__ h,
    const float* __restrict__ sums, const float* __restrict__ gamma,
    const float* __restrict__ beta, float* __restrict__ xout, int nN) {
  int idx = blockIdx.x * 256 + threadIdx.x;
  int total = nN * (DIM / 4);
  if (idx >= total) return;
  int c = (idx & 31) * 4;
  float invN = 1.0f / (float)nN;
  float4 hv = reinterpret_cast<const float4*>(h)[idx];
  const float* hp = reinterpret_cast<const float*>(&hv);
  float4 o;
  float* op = reinterpret_cast<float*>(&o);
#pragma unroll
  for (int j = 0; j < 4; ++j) {
    float mu = sums[c + j] * invN;
    float var = sums[DIM + c + j] * invN - mu * mu;
    float sc = gamma[c + j] * rsqrtf(var + EPS);
    float sh = beta[c + j] - mu * sc;
    op[j] = fmaxf(hp[j] * sc + sh, 0.0f);
  }
  reinterpret_cast<float4*>(xout)[idx] = o;
}

// batch is sorted: one block per graph, binary-search the contiguous range.
__global__ __launch_bounds__(256) void pool_kernel(const float* __restrict__ x,
    const int* __restrict__ batch, float* __restrict__ out, int nN) {
  __shared__ int s_lo, s_hi;
  __shared__ float s_acc[256];
  int g = blockIdx.x;
  if (threadIdx.x == 0) {
    s_lo = lower_bound_i(batch, nN, g);
    s_hi = lower_bound_i(batch, nN, g + 1);
  }
  __syncthreads();
  int lo = s_lo, hi = s_hi;
  int c = threadIdx.x & 127;
  int rp = threadIdx.x >> 7;
  float acc = 0.f;
  for (int r = lo + rp; r < hi; r += 2) acc += x[(size_t)r * DIM + c];
  s_acc[threadIdx.x] = acc;
  __syncthreads();
  if (threadIdx.x < 128) {
    float v = s_acc[threadIdx.x] + s_acc[threadIdx.x + 128];
    float cnt = fmaxf((float)(hi - lo), 1.0f);
    out[(size_t)g * DIM + c] = v / cnt;
  }
}

extern "C" void kernel_launch(void* const* d_in, const int* in_sizes, int n_in,
                              void* d_out, int out_size, void* d_ws, size_t ws_size,
                              hipStream_t stream) {
  const float* x     = (const float*)d_in[0];
  const int*   ei    = (const int*)d_in[1];
  const int*   batch = (const int*)d_in[2];
  const float* W_l   = (const float*)d_in[3];
  const float* b_l   = (const float*)d_in[4];
  const float* W_r   = (const float*)d_in[5];
  const float* gamma = (const float*)d_in[6];
  const float* beta  = (const float*)d_in[7];
  float* out = (float*)d_out;

  const int N = in_sizes[2];
  const int E = in_sizes[1] / 2;
  const int G = out_size / DIM;
  const int L = in_sizes[3] / (DIM * DIM);

  const int* src  = ei;
  const int* dstE = ei + E;

  float* ws   = (float*)d_ws;
  float* deg  = ws;                       // N
  float* agg  = deg + N;                  // N*DIM
  float* h    = agg + (size_t)N * DIM;    // N*DIM
  float* xb   = h + (size_t)N * DIM;      // N*DIM
  float* sums = xb + (size_t)N * DIM;     // 2*DIM

  hipMemsetAsync(deg, 0, (size_t)N * sizeof(float), stream);
  deg_kernel<<<(E + 255) / 256, 256, 0, stream>>>(dstE, deg, E);

  const float* xin = x;
  for (int l = 0; l < L; ++l) {
    hipMemsetAsync(agg, 0, (size_t)N * DIM * sizeof(float), stream);
    scatter_kernel<<<(E * 32 + 255) / 256, 256, 0, stream>>>(xin, src, dstE, agg, E);
    gemm_kernel<<<(N + 15) / 16, 256, 0, stream>>>(agg, deg, xin,
        W_l + (size_t)l * DIM * DIM, b_l + (size_t)l * DIM,
        W_r + (size_t)l * DIM * DIM, h, N);
    hipMemsetAsync(sums, 0, 2 * DIM * sizeof(float), stream);
    stats_kernel<<<240, 256, 0, stream>>>(h, sums, N);
    bn_relu_kernel<<<(N * (DIM / 4) + 255) / 256, 256, 0, stream>>>(
        h, sums, gamma + (size_t)l * DIM, beta + (size_t)l * DIM, xb, N);
    xin = xb;
  }
  pool_kernel<<<G, 256, 0, stream>>>(xin, batch, out, N);
}

// Round 2
// 651.934 us; speedup vs baseline: 3.9064x; 3.9064x over previous
//
#include <hip/hip_runtime.h>

#define DIM 128
#define EPS 1e-5f
#define SCAN_T 1024

__device__ __forceinline__ int lower_bound_i(const int* __restrict__ a, int n, int key) {
  int lo = 0, hi = n;
  while (lo < hi) {
    int mid = (lo + hi) >> 1;
    if (a[mid] < key) lo = mid + 1; else hi = mid;
  }
  return lo;
}

// --- CSR build -------------------------------------------------------------
__global__ __launch_bounds__(256) void hist_kernel(const int* __restrict__ dst,
                                                   int* __restrict__ cnt, int nE) {
  int i = blockIdx.x * 256 + threadIdx.x;
  if (i < nE) atomicAdd(&cnt[dst[i]], 1);
}

// Exclusive prefix sum of cnt[0..nN) -> rowptr[0..nN]; single block.
__global__ __launch_bounds__(SCAN_T) void scan_kernel(const int* __restrict__ cnt,
                                                      int* __restrict__ rowptr, int nN) {
  __shared__ int s[SCAN_T];
  int t = threadIdx.x;
  int chunk = (nN + SCAN_T - 1) / SCAN_T;
  int lo = t * chunk, hi = min(lo + chunk, nN);
  int sum = 0;
  for (int i = lo; i < hi; ++i) sum += cnt[i];
  s[t] = sum;
  __syncthreads();
  for (int off = 1; off < SCAN_T; off <<= 1) {
    int v = (t >= off) ? s[t - off] : 0;
    __syncthreads();
    s[t] += v;
    __syncthreads();
  }
  int base = (t > 0) ? s[t - 1] : 0;
  for (int i = lo; i < hi; ++i) { rowptr[i] = base; base += cnt[i]; }
  if (t == SCAN_T - 1) rowptr[nN] = base;
}

__global__ __launch_bounds__(256) void fill_kernel(const int* __restrict__ src,
    const int* __restrict__ dst, const int* __restrict__ rowptr,
    int* __restrict__ cursor, int* __restrict__ eidx, int nE) {
  int e = blockIdx.x * 256 + threadIdx.x;
  if (e < nE) {
    int d = dst[e];
    int p = atomicAdd(&cursor[d], 1);
    eidx[rowptr[d] + p] = src[e];
  }
}

// --- mean-aggregate via gather: 32 threads per dst node --------------------
__global__ __launch_bounds__(256) void gather_kernel(const float* __restrict__ x,
    const int* __restrict__ rowptr, const int* __restrict__ eidx,
    float* __restrict__ agg, int nN) {
  int grp = (blockIdx.x * 256 + threadIdx.x) >> 5;
  int j = threadIdx.x & 31;
  if (grp >= nN) return;
  int lo = rowptr[grp], hi = rowptr[grp + 1];
  float4 acc = make_float4(0.f, 0.f, 0.f, 0.f);
  for (int i = lo; i < hi; ++i) {
    int s = eidx[i];
    float4 v = reinterpret_cast<const float4*>(x)[(size_t)s * 32 + j];
    acc.x += v.x; acc.y += v.y; acc.z += v.z; acc.w += v.w;
  }
  float invd = 1.0f / fmaxf((float)(hi - lo), 1.0f);
  acc.x *= invd; acc.y *= invd; acc.z *= invd; acc.w *= invd;
  reinterpret_cast<float4*>(agg)[(size_t)grp * 32 + j] = acc;
}

// h[n][c] = agg[n][:] @ Wl[:, c] + bias[c] + x[n][:] @ Wr[:, c]
__global__ __launch_bounds__(256) void gemm_kernel(const float* __restrict__ agg,
    const float* __restrict__ x,
    const float* __restrict__ Wl, const float* __restrict__ bias,
    const float* __restrict__ Wr, float* __restrict__ h, int nN) {
  __shared__ float a_sh[16][DIM];
  __shared__ float x_sh[16][DIM];
  const int tid = threadIdx.x;
  const int n0 = blockIdx.x * 16;
#pragma unroll
  for (int i = 0; i < 8; ++i) {
    int idx = tid + i * 256;
    int lr = idx >> 7, cc = idx & 127;
    int n = n0 + lr;
    if (n >= nN) n = nN - 1;
    a_sh[lr][cc] = agg[(size_t)n * DIM + cc];
    x_sh[lr][cc] = x[(size_t)n * DIM + cc];
  }
  __syncthreads();
  const int c4 = (tid & 31) * 4;
  const int rg = tid >> 5;
  float acc0[4], acc1[4];
#pragma unroll
  for (int j = 0; j < 4; ++j) { acc0[j] = bias[c4 + j]; acc1[j] = acc0[j]; }
  for (int kb = 0; kb < DIM; kb += 4) {
    float4 a0 = *reinterpret_cast<const float4*>(&a_sh[rg][kb]);
    float4 a1 = *reinterpret_cast<const float4*>(&a_sh[rg + 8][kb]);
    float4 x0 = *reinterpret_cast<const float4*>(&x_sh[rg][kb]);
    float4 x1 = *reinterpret_cast<const float4*>(&x_sh[rg + 8][kb]);
    const float* a0p = reinterpret_cast<const float*>(&a0);
    const float* a1p = reinterpret_cast<const float*>(&a1);
    const float* x0p = reinterpret_cast<const float*>(&x0);
    const float* x1p = reinterpret_cast<const float*>(&x1);
#pragma unroll
    for (int kk = 0; kk < 4; ++kk) {
      float4 wl = *reinterpret_cast<const float4*>(&Wl[(size_t)(kb + kk) * DIM + c4]);
      float4 wr = *reinterpret_cast<const float4*>(&Wr[(size_t)(kb + kk) * DIM + c4]);
      float av0 = a0p[kk], av1 = a1p[kk];
      float xv0 = x0p[kk], xv1 = x1p[kk];
      acc0[0] += av0 * wl.x + xv0 * wr.x;
      acc0[1] += av0 * wl.y + xv0 * wr.y;
      acc0[2] += av0 * wl.z + xv0 * wr.z;
      acc0[3] += av0 * wl.w + xv0 * wr.w;
      acc1[0] += av1 * wl.x + xv1 * wr.x;
      acc1[1] += av1 * wl.y + xv1 * wr.y;
      acc1[2] += av1 * wl.z + xv1 * wr.z;
      acc1[3] += av1 * wl.w + xv1 * wr.w;
    }
  }
  int r0 = n0 + rg, r1 = n0 + rg + 8;
  if (r0 < nN) {
    float4 o = make_float4(acc0[0], acc0[1], acc0[2], acc0[3]);
    *reinterpret_cast<float4*>(&h[(size_t)r0 * DIM + c4]) = o;
  }
  if (r1 < nN) {
    float4 o = make_float4(acc1[0], acc1[1], acc1[2], acc1[3]);
    *reinterpret_cast<float4*>(&h[(size_t)r1 * DIM + c4]) = o;
  }
}

__global__ __launch_bounds__(256) void stats_kernel(const float* __restrict__ h,
                                                    float* __restrict__ sums, int nN) {
  __shared__ float s_s[256];
  __shared__ float s_q[256];
  int tid = threadIdx.x;
  int c = tid & 127;
  int rp = tid >> 7;
  float ls = 0.f, lq = 0.f;
  for (int r = blockIdx.x * 2 + rp; r < nN; r += gridDim.x * 2) {
    float v = h[(size_t)r * DIM + c];
    ls += v;
    lq += v * v;
  }
  s_s[tid] = ls;
  s_q[tid] = lq;
  __syncthreads();
  if (tid < 128) {
    atomicAdd(&sums[c], s_s[tid] + s_s[tid + 128]);
    atomicAdd(&sums[DIM + c], s_q[tid] + s_q[tid + 128]);
  }
}

__global__ __launch_bounds__(256) void bn_relu_kernel(const float* __restrict__ h,
    const float* __restrict__ sums, const float* __restrict__ gamma,
    const float* __restrict__ beta, float* __restrict__ xout, int nN) {
  int idx = blockIdx.x * 256 + threadIdx.x;
  int total = nN * (DIM / 4);
  if (idx >= total) return;
  int c = (idx & 31) * 4;
  float invN = 1.0f / (float)nN;
  float4 hv = reinterpret_cast<const float4*>(h)[idx];
  const float* hp = reinterpret_cast<const float*>(&hv);
  float4 o;
  float* op = reinterpret_cast<float*>(&o);
#pragma unroll
  for (int j = 0; j < 4; ++j) {
    float mu = sums[c + j] * invN;
    float var = sums[DIM + c + j] * invN - mu * mu;
    float sc = gamma[c + j] * rsqrtf(var + EPS);
    float sh = beta[c + j] - mu * sc;
    op[j] = fmaxf(hp[j] * sc + sh, 0.0f);
  }
  reinterpret_cast<float4*>(xout)[idx] = o;
}

__global__ __launch_bounds__(256) void pool_kernel(const float* __restrict__ x,
    const int* __restrict__ batch, float* __restrict__ out, int nN) {
  __shared__ int s_lo, s_hi;
  __shared__ float s_acc[256];
  int g = blockIdx.x;
  if (threadIdx.x == 0) {
    s_lo = lower_bound_i(batch, nN, g);
    s_hi = lower_bound_i(batch, nN, g + 1);
  }
  __syncthreads();
  int lo = s_lo, hi = s_hi;
  int c = threadIdx.x & 127;
  int rp = threadIdx.x >> 7;
  float acc = 0.f;
  for (int r = lo + rp; r < hi; r += 2) acc += x[(size_t)r * DIM + c];
  s_acc[threadIdx.x] = acc;
  __syncthreads();
  if (threadIdx.x < 128) {
    float v = s_acc[threadIdx.x] + s_acc[threadIdx.x + 128];
    float cnt = fmaxf((float)(hi - lo), 1.0f);
    out[(size_t)g * DIM + c] = v / cnt;
  }
}

extern "C" void kernel_launch(void* const* d_in, const int* in_sizes, int n_in,
                              void* d_out, int out_size, void* d_ws, size_t ws_size,
                              hipStream_t stream) {
  const float* x     = (const float*)d_in[0];
  const int*   ei    = (const int*)d_in[1];
  const int*   batch = (const int*)d_in[2];
  const float* W_l   = (const float*)d_in[3];
  const float* b_l   = (const float*)d_in[4];
  const float* W_r   = (const float*)d_in[5];
  const float* gamma = (const float*)d_in[6];
  const float* beta  = (const float*)d_in[7];
  float* out = (float*)d_out;

  const int N = in_sizes[2];
  const int E = in_sizes[1] / 2;
  const int G = out_size / DIM;
  const int L = in_sizes[3] / (DIM * DIM);

  const int* src  = ei;
  const int* dstE = ei + E;

  // workspace layout
  char* wsb = (char*)d_ws;
  float* agg  = (float*)wsb;                      wsb += (size_t)N * DIM * sizeof(float);
  float* h    = (float*)wsb;                      wsb += (size_t)N * DIM * sizeof(float);
  float* xb   = (float*)wsb;                      wsb += (size_t)N * DIM * sizeof(float);
  float* sums = (float*)wsb;                      wsb += 2 * DIM * sizeof(float);
  int* cnt    = (int*)wsb;                        wsb += (size_t)N * sizeof(int);
  int* rowptr = (int*)wsb;                        wsb += (size_t)(N + 1) * sizeof(int);
  int* cursor = (int*)wsb;                        wsb += (size_t)N * sizeof(int);
  int* eidx   = (int*)wsb;                        wsb += (size_t)E * sizeof(int);

  // CSR build (per-call; deterministic)
  hipMemsetAsync(cnt, 0, (size_t)N * sizeof(int), stream);
  hipMemsetAsync(cursor, 0, (size_t)N * sizeof(int), stream);
  hist_kernel<<<(E + 255) / 256, 256, 0, stream>>>(dstE, cnt, E);
  scan_kernel<<<1, SCAN_T, 0, stream>>>(cnt, rowptr, N);
  fill_kernel<<<(E + 255) / 256, 256, 0, stream>>>(src, dstE, rowptr, cursor, eidx, E);

  const float* xin = x;
  for (int l = 0; l < L; ++l) {
    gather_kernel<<<(N * 32 + 255) / 256, 256, 0, stream>>>(xin, rowptr, eidx, agg, N);
    gemm_kernel<<<(N + 15) / 16, 256, 0, stream>>>(agg, xin,
        W_l + (size_t)l * DIM * DIM, b_l + (size_t)l * DIM,
        W_r + (size_t)l * DIM * DIM, h, N);
    hipMemsetAsync(sums, 0, 2 * DIM * sizeof(float), stream);
    stats_kernel<<<240, 256, 0, stream>>>(h, sums, N);
    bn_relu_kernel<<<(N * (DIM / 4) + 255) / 256, 256, 0, stream>>>(
        h, sums, gamma + (size_t)l * DIM, beta + (size_t)l * DIM, xb, N);
    xin = xb;
  }
  pool_kernel<<<G, 256, 0, stream>>>(xin, batch, out, N);
}

// Round 3
// 525.322 us; speedup vs baseline: 4.8480x; 1.2410x over previous
//
#include <hip/hip_runtime.h>

#define DIM 128
#define EPS 1e-5f
#define SCAN_T 1024

typedef short s16x8 __attribute__((ext_vector_type(8)));
typedef float f32x4 __attribute__((ext_vector_type(4)));

__device__ __forceinline__ int lower_bound_i(const int* __restrict__ a, int n, int key) {
  int lo = 0, hi = n;
  while (lo < hi) {
    int mid = (lo + hi) >> 1;
    if (a[mid] < key) lo = mid + 1; else hi = mid;
  }
  return lo;
}

__device__ __forceinline__ unsigned rne_bf16(float f) {
  unsigned u = __builtin_bit_cast(unsigned, f);
  return (u + 0x7fffu + ((u >> 16) & 1u)) >> 16;
}
__device__ __forceinline__ float bf16_hi_to_f32(unsigned h) {
  return __builtin_bit_cast(float, h << 16);
}

// split 8 consecutive fp32 into hi/lo bf16 fragments
__device__ __forceinline__ void split_frag(const float* __restrict__ base,
                                           s16x8& hi, s16x8& lo) {
  float4 f0 = *reinterpret_cast<const float4*>(base);
  float4 f1 = *reinterpret_cast<const float4*>(base + 4);
  float v[8] = {f0.x, f0.y, f0.z, f0.w, f1.x, f1.y, f1.z, f1.w};
#pragma unroll
  for (int j = 0; j < 8; ++j) {
    unsigned h = rne_bf16(v[j]);
    float r = v[j] - bf16_hi_to_f32(h);
    hi[j] = (short)h;
    lo[j] = (short)rne_bf16(r);
  }
}

// --- CSR build -------------------------------------------------------------
__global__ __launch_bounds__(256) void hist_kernel(const int* __restrict__ dst,
                                                   int* __restrict__ cnt, int nE) {
  int i = blockIdx.x * 256 + threadIdx.x;
  if (i < nE) atomicAdd(&cnt[dst[i]], 1);
}

__global__ __launch_bounds__(SCAN_T) void scan_kernel(const int* __restrict__ cnt,
                                                      int* __restrict__ rowptr, int nN) {
  __shared__ int s[SCAN_T];
  int t = threadIdx.x;
  int chunk = (nN + SCAN_T - 1) / SCAN_T;
  int lo = t * chunk, hi = min(lo + chunk, nN);
  int sum = 0;
  for (int i = lo; i < hi; ++i) sum += cnt[i];
  s[t] = sum;
  __syncthreads();
  for (int off = 1; off < SCAN_T; off <<= 1) {
    int v = (t >= off) ? s[t - off] : 0;
    __syncthreads();
    s[t] += v;
    __syncthreads();
  }
  int base = (t > 0) ? s[t - 1] : 0;
  for (int i = lo; i < hi; ++i) { rowptr[i] = base; base += cnt[i]; }
  if (t == SCAN_T - 1) rowptr[nN] = base;
}

__global__ __launch_bounds__(256) void fill_kernel(const int* __restrict__ src,
    const int* __restrict__ dst, const int* __restrict__ rowptr,
    int* __restrict__ cursor, int* __restrict__ eidx, int nE) {
  int e = blockIdx.x * 256 + threadIdx.x;
  if (e < nE) {
    int d = dst[e];
    int p = atomicAdd(&cursor[d], 1);
    eidx[rowptr[d] + p] = src[e];
  }
}

// --- mean-aggregate via gather: 32 threads per dst node --------------------
__global__ __launch_bounds__(256) void gather_kernel(const float* __restrict__ x,
    const int* __restrict__ rowptr, const int* __restrict__ eidx,
    float* __restrict__ agg, int nN) {
  int grp = (blockIdx.x * 256 + threadIdx.x) >> 5;
  int j = threadIdx.x & 31;
  if (grp >= nN) return;
  int lo = rowptr[grp], hi = rowptr[grp + 1];
  float4 acc = make_float4(0.f, 0.f, 0.f, 0.f);
  int i = lo;
  for (; i + 1 < hi; i += 2) {
    int s0 = eidx[i], s1 = eidx[i + 1];
    float4 v0 = reinterpret_cast<const float4*>(x)[(size_t)s0 * 32 + j];
    float4 v1 = reinterpret_cast<const float4*>(x)[(size_t)s1 * 32 + j];
    acc.x += v0.x; acc.y += v0.y; acc.z += v0.z; acc.w += v0.w;
    acc.x += v1.x; acc.y += v1.y; acc.z += v1.z; acc.w += v1.w;
  }
  if (i < hi) {
    int s0 = eidx[i];
    float4 v0 = reinterpret_cast<const float4*>(x)[(size_t)s0 * 32 + j];
    acc.x += v0.x; acc.y += v0.y; acc.z += v0.z; acc.w += v0.w;
  }
  float invd = 1.0f / fmaxf((float)(hi - lo), 1.0f);
  acc.x *= invd; acc.y *= invd; acc.z *= invd; acc.w *= invd;
  reinterpret_cast<float4*>(agg)[(size_t)grp * 32 + j] = acc;
}

// --- W prep: W^T concat [Wl;Wr] -> Wt[c][k] (k=0..255), split hi/lo bf16 ----
__global__ __launch_bounds__(256) void cvt_w_kernel(const float* __restrict__ Wl,
    const float* __restrict__ Wr, unsigned short* __restrict__ Wth,
    unsigned short* __restrict__ Wtl) {
  int idx = blockIdx.x * 256 + threadIdx.x;  // c*256 + k
  if (idx >= DIM * 256) return;
  int c = idx >> 8, k = idx & 255;
  float v = (k < DIM) ? Wl[(size_t)k * DIM + c] : Wr[(size_t)(k - DIM) * DIM + c];
  unsigned h = rne_bf16(v);
  float r = v - bf16_hi_to_f32(h);
  Wth[idx] = (unsigned short)h;
  Wtl[idx] = (unsigned short)rne_bf16(r);
}

// --- fused dual-GEMM via bf16 split-precision MFMA --------------------------
// h[n][c] = [A0|A1](n,:) @ Wt^T(:,c) + bias[c], K=256
// Block: 256 threads = 4 waves; block tile 128 rows x 128 cols.
// Wave: 32 rows (2 x 16-row MFMA tiles) x 128 cols (8 x 16-col tiles).
__global__ __launch_bounds__(256) void gemm_mfma_kernel(
    const float* __restrict__ A0, const float* __restrict__ A1,
    const unsigned short* __restrict__ Wth, const unsigned short* __restrict__ Wtl,
    const float* __restrict__ bias, float* __restrict__ h, int nN) {
  const int lane = threadIdx.x & 63;
  const int wave = threadIdx.x >> 6;
  const int rbase = blockIdx.x * 128 + wave * 32;
  const int lrow = lane & 15;
  const int koff = (lane >> 4) * 8;

  f32x4 acc[2][8];
#pragma unroll
  for (int rt = 0; rt < 2; ++rt)
#pragma unroll
    for (int ct = 0; ct < 8; ++ct)
      acc[rt][ct] = (f32x4){0.f, 0.f, 0.f, 0.f};

  int r0 = rbase + lrow;      if (r0 > nN - 1) r0 = nN - 1;
  int r1 = rbase + 16 + lrow; if (r1 > nN - 1) r1 = nN - 1;

#pragma unroll
  for (int s = 0; s < 2; ++s) {
    const float* A = s ? A1 : A0;
    const float* a0p = A + (size_t)r0 * DIM;
    const float* a1p = A + (size_t)r1 * DIM;
#pragma unroll
    for (int ks = 0; ks < 4; ++ks) {
      int ka = ks * 32 + koff;
      int kw = s * 128 + ka;
      s16x8 ah0, al0, ah1, al1;
      split_frag(a0p + ka, ah0, al0);
      split_frag(a1p + ka, ah1, al1);
#pragma unroll
      for (int ct = 0; ct < 8; ++ct) {
        int c = ct * 16 + lrow;
        s16x8 wh = *reinterpret_cast<const s16x8*>(Wth + (size_t)c * 256 + kw);
        s16x8 wl = *reinterpret_cast<const s16x8*>(Wtl + (size_t)c * 256 + kw);
        acc[0][ct] = __builtin_amdgcn_mfma_f32_16x16x32_bf16(ah0, wh, acc[0][ct], 0, 0, 0);
        acc[0][ct] = __builtin_amdgcn_mfma_f32_16x16x32_bf16(ah0, wl, acc[0][ct], 0, 0, 0);
        acc[0][ct] = __builtin_amdgcn_mfma_f32_16x16x32_bf16(al0, wh, acc[0][ct], 0, 0, 0);
        acc[1][ct] = __builtin_amdgcn_mfma_f32_16x16x32_bf16(ah1, wh, acc[1][ct], 0, 0, 0);
        acc[1][ct] = __builtin_amdgcn_mfma_f32_16x16x32_bf16(ah1, wl, acc[1][ct], 0, 0, 0);
        acc[1][ct] = __builtin_amdgcn_mfma_f32_16x16x32_bf16(al1, wh, acc[1][ct], 0, 0, 0);
      }
    }
  }

#pragma unroll
  for (int ct = 0; ct < 8; ++ct) {
    int c = ct * 16 + lrow;
    float b = bias[c];
#pragma unroll
    for (int rt = 0; rt < 2; ++rt) {
      int rr = rbase + rt * 16 + (lane >> 4) * 4;
#pragma unroll
      for (int j = 0; j < 4; ++j) {
        int row = rr + j;
        if (row < nN) h[(size_t)row * DIM + c] = acc[rt][ct][j] + b;
      }
    }
  }
}

__global__ __launch_bounds__(256) void stats_kernel(const float* __restrict__ h,
                                                    float* __restrict__ sums, int nN) {
  __shared__ float s_s[256];
  __shared__ float s_q[256];
  int tid = threadIdx.x;
  int c = tid & 127;
  int rp = tid >> 7;
  float ls = 0.f, lq = 0.f;
  for (int r = blockIdx.x * 2 + rp; r < nN; r += gridDim.x * 2) {
    float v = h[(size_t)r * DIM + c];
    ls += v;
    lq += v * v;
  }
  s_s[tid] = ls;
  s_q[tid] = lq;
  __syncthreads();
  if (tid < 128) {
    atomicAdd(&sums[c], s_s[tid] + s_s[tid + 128]);
    atomicAdd(&sums[DIM + c], s_q[tid] + s_q[tid + 128]);
  }
}

__global__ __launch_bounds__(256) void bn_relu_kernel(const float* __restrict__ h,
    const float* __restrict__ sums, const float* __restrict__ gamma,
    const float* __restrict__ beta, float* __restrict__ xout, int nN) {
  int idx = blockIdx.x * 256 + threadIdx.x;
  int total = nN * (DIM / 4);
  if (idx >= total) return;
  int c = (idx & 31) * 4;
  float invN = 1.0f / (float)nN;
  float4 hv = reinterpret_cast<const float4*>(h)[idx];
  const float* hp = reinterpret_cast<const float*>(&hv);
  float4 o;
  float* op = reinterpret_cast<float*>(&o);
#pragma unroll
  for (int j = 0; j < 4; ++j) {
    float mu = sums[c + j] * invN;
    float var = sums[DIM + c + j] * invN - mu * mu;
    float sc = gamma[c + j] * rsqrtf(var + EPS);
    float sh = beta[c + j] - mu * sc;
    op[j] = fmaxf(hp[j] * sc + sh, 0.0f);
  }
  reinterpret_cast<float4*>(xout)[idx] = o;
}

__global__ __launch_bounds__(256) void pool_kernel(const float* __restrict__ x,
    const int* __restrict__ batch, float* __restrict__ out, int nN) {
  __shared__ int s_lo, s_hi;
  __shared__ float s_acc[256];
  int g = blockIdx.x;
  if (threadIdx.x == 0) {
    s_lo = lower_bound_i(batch, nN, g);
    s_hi = lower_bound_i(batch, nN, g + 1);
  }
  __syncthreads();
  int lo = s_lo, hi = s_hi;
  int c = threadIdx.x & 127;
  int rp = threadIdx.x >> 7;
  float acc = 0.f;
  for (int r = lo + rp; r < hi; r += 2) acc += x[(size_t)r * DIM + c];
  s_acc[threadIdx.x] = acc;
  __syncthreads();
  if (threadIdx.x < 128) {
    float v = s_acc[threadIdx.x] + s_acc[threadIdx.x + 128];
    float cnt = fmaxf((float)(hi - lo), 1.0f);
    out[(size_t)g * DIM + c] = v / cnt;
  }
}

extern "C" void kernel_launch(void* const* d_in, const int* in_sizes, int n_in,
                              void* d_out, int out_size, void* d_ws, size_t ws_size,
                              hipStream_t stream) {
  const float* x     = (const float*)d_in[0];
  const int*   ei    = (const int*)d_in[1];
  const int*   batch = (const int*)d_in[2];
  const float* W_l   = (const float*)d_in[3];
  const float* b_l   = (const float*)d_in[4];
  const float* W_r   = (const float*)d_in[5];
  const float* gamma = (const float*)d_in[6];
  const float* beta  = (const float*)d_in[7];
  float* out = (float*)d_out;

  const int N = in_sizes[2];
  const int E = in_sizes[1] / 2;
  const int G = out_size / DIM;
  const int L = in_sizes[3] / (DIM * DIM);

  const int* src  = ei;
  const int* dstE = ei + E;

  // workspace layout
  char* wsb = (char*)d_ws;
  float* agg  = (float*)wsb;  wsb += (size_t)N * DIM * sizeof(float);
  float* h    = (float*)wsb;  wsb += (size_t)N * DIM * sizeof(float);
  float* xb   = (float*)wsb;  wsb += (size_t)N * DIM * sizeof(float);
  float* sums = (float*)wsb;  wsb += 2 * DIM * sizeof(float);
  int* cnt    = (int*)wsb;    wsb += (size_t)N * sizeof(int);
  int* rowptr = (int*)wsb;    wsb += (size_t)(N + 1) * sizeof(int);
  int* cursor = (int*)wsb;    wsb += (size_t)N * sizeof(int);
  int* eidx   = (int*)wsb;    wsb += (size_t)E * sizeof(int);
  unsigned short* Wth = (unsigned short*)wsb; wsb += (size_t)DIM * 256 * sizeof(unsigned short);
  unsigned short* Wtl = (unsigned short*)wsb; wsb += (size_t)DIM * 256 * sizeof(unsigned short);

  // CSR build
  hipMemsetAsync(cnt, 0, (size_t)N * sizeof(int), stream);
  hipMemsetAsync(cursor, 0, (size_t)N * sizeof(int), stream);
  hist_kernel<<<(E + 255) / 256, 256, 0, stream>>>(dstE, cnt, E);
  scan_kernel<<<1, SCAN_T, 0, stream>>>(cnt, rowptr, N);
  fill_kernel<<<(E + 255) / 256, 256, 0, stream>>>(src, dstE, rowptr, cursor, eidx, E);

  const float* xin = x;
  for (int l = 0; l < L; ++l) {
    cvt_w_kernel<<<(DIM * 256 + 255) / 256, 256, 0, stream>>>(
        W_l + (size_t)l * DIM * DIM, W_r + (size_t)l * DIM * DIM, Wth, Wtl);
    gather_kernel<<<(N * 32 + 255) / 256, 256, 0, stream>>>(xin, rowptr, eidx, agg, N);
    gemm_mfma_kernel<<<(N + 127) / 128, 256, 0, stream>>>(agg, xin, Wth, Wtl,
        b_l + (size_t)l * DIM, h, N);
    hipMemsetAsync(sums, 0, 2 * DIM * sizeof(float), stream);
    stats_kernel<<<240, 256, 0, stream>>>(h, sums, N);
    bn_relu_kernel<<<(N * (DIM / 4) + 255) / 256, 256, 0, stream>>>(
        h, sums, gamma + (size_t)l * DIM, beta + (size_t)l * DIM, xb, N);
    xin = xb;
  }
  pool_kernel<<<G, 256, 0, stream>>>(xin, batch, out, N);
}

// Round 4
// 427.666 us; speedup vs baseline: 5.9550x; 1.2283x over previous
//
#include <hip/hip_runtime.h>

#define DIM 128
#define EPS 1e-5f
#define SCAN_T 1024

typedef short s16x8 __attribute__((ext_vector_type(8)));
typedef float f32x4 __attribute__((ext_vector_type(4)));

__device__ __forceinline__ int lower_bound_i(const int* __restrict__ a, int n, int key) {
  int lo = 0, hi = n;
  while (lo < hi) {
    int mid = (lo + hi) >> 1;
    if (a[mid] < key) lo = mid + 1; else hi = mid;
  }
  return lo;
}

__device__ __forceinline__ unsigned rne_bf16(float f) {
  unsigned u = __builtin_bit_cast(unsigned, f);
  return (u + 0x7fffu + ((u >> 16) & 1u)) >> 16;
}
__device__ __forceinline__ float bf16_hi_to_f32(unsigned h) {
  return __builtin_bit_cast(float, h << 16);
}

__device__ __forceinline__ void split_frag(const float* __restrict__ base,
                                           s16x8& hi, s16x8& lo) {
  float4 f0 = *reinterpret_cast<const float4*>(base);
  float4 f1 = *reinterpret_cast<const float4*>(base + 4);
  float v[8] = {f0.x, f0.y, f0.z, f0.w, f1.x, f1.y, f1.z, f1.w};
#pragma unroll
  for (int j = 0; j < 8; ++j) {
    unsigned h = rne_bf16(v[j]);
    float r = v[j] - bf16_hi_to_f32(h);
    hi[j] = (short)h;
    lo[j] = (short)rne_bf16(r);
  }
}

// --- CSR build -------------------------------------------------------------
__global__ __launch_bounds__(256) void hist_kernel(const int* __restrict__ dst,
                                                   int* __restrict__ cnt, int nE) {
  int i = blockIdx.x * 256 + threadIdx.x;
  if (i < nE) atomicAdd(&cnt[dst[i]], 1);
}

__global__ __launch_bounds__(SCAN_T) void scan_kernel(const int* __restrict__ cnt,
                                                      int* __restrict__ rowptr, int nN) {
  __shared__ int s[SCAN_T];
  int t = threadIdx.x;
  int chunk = (nN + SCAN_T - 1) / SCAN_T;
  int lo = t * chunk, hi = min(lo + chunk, nN);
  int sum = 0;
  for (int i = lo; i < hi; ++i) sum += cnt[i];
  s[t] = sum;
  __syncthreads();
  for (int off = 1; off < SCAN_T; off <<= 1) {
    int v = (t >= off) ? s[t - off] : 0;
    __syncthreads();
    s[t] += v;
    __syncthreads();
  }
  int base = (t > 0) ? s[t - 1] : 0;
  for (int i = lo; i < hi; ++i) { rowptr[i] = base; base += cnt[i]; }
  if (t == SCAN_T - 1) rowptr[nN] = base;
}

__global__ __launch_bounds__(256) void fill_kernel(const int* __restrict__ src,
    const int* __restrict__ dst, const int* __restrict__ rowptr,
    int* __restrict__ cursor, int* __restrict__ eidx, int nE) {
  int e = blockIdx.x * 256 + threadIdx.x;
  if (e < nE) {
    int d = dst[e];
    int p = atomicAdd(&cursor[d], 1);
    eidx[rowptr[d] + p] = src[e];
  }
}

// --- mean-aggregate via gather: 32 threads per dst node --------------------
__global__ __launch_bounds__(256) void gather_kernel(const float* __restrict__ x,
    const int* __restrict__ rowptr, const int* __restrict__ eidx,
    float* __restrict__ agg, int nN) {
  int grp = (blockIdx.x * 256 + threadIdx.x) >> 5;
  int j = threadIdx.x & 31;
  if (grp >= nN) return;
  int lo = rowptr[grp], hi = rowptr[grp + 1];
  float4 acc = make_float4(0.f, 0.f, 0.f, 0.f);
  int i = lo;
  for (; i + 1 < hi; i += 2) {
    int s0 = eidx[i], s1 = eidx[i + 1];
    float4 v0 = reinterpret_cast<const float4*>(x)[(size_t)s0 * 32 + j];
    float4 v1 = reinterpret_cast<const float4*>(x)[(size_t)s1 * 32 + j];
    acc.x += v0.x; acc.y += v0.y; acc.z += v0.z; acc.w += v0.w;
    acc.x += v1.x; acc.y += v1.y; acc.z += v1.z; acc.w += v1.w;
  }
  if (i < hi) {
    int s0 = eidx[i];
    float4 v0 = reinterpret_cast<const float4*>(x)[(size_t)s0 * 32 + j];
    acc.x += v0.x; acc.y += v0.y; acc.z += v0.z; acc.w += v0.w;
  }
  float invd = 1.0f / fmaxf((float)(hi - lo), 1.0f);
  acc.x *= invd; acc.y *= invd; acc.z *= invd; acc.w *= invd;
  reinterpret_cast<float4*>(agg)[(size_t)grp * 32 + j] = acc;
}

// --- W prep ---------------------------------------------------------------
__global__ __launch_bounds__(256) void cvt_w_kernel(const float* __restrict__ Wl,
    const float* __restrict__ Wr, unsigned short* __restrict__ Wth,
    unsigned short* __restrict__ Wtl) {
  int idx = blockIdx.x * 256 + threadIdx.x;  // c*256 + k
  if (idx >= DIM * 256) return;
  int c = idx >> 8, k = idx & 255;
  float v = (k < DIM) ? Wl[(size_t)k * DIM + c] : Wr[(size_t)(k - DIM) * DIM + c];
  unsigned h = rne_bf16(v);
  float r = v - bf16_hi_to_f32(h);
  Wth[idx] = (unsigned short)h;
  Wtl[idx] = (unsigned short)rne_bf16(r);
}

// --- fused dual-GEMM via bf16 split-precision MFMA --------------------------
__global__ __launch_bounds__(256) void gemm_mfma_kernel(
    const float* __restrict__ A0, const float* __restrict__ A1,
    const unsigned short* __restrict__ Wth, const unsigned short* __restrict__ Wtl,
    const float* __restrict__ bias, float* __restrict__ h, int nN) {
  const int lane = threadIdx.x & 63;
  const int wave = threadIdx.x >> 6;
  const int rbase = blockIdx.x * 128 + wave * 32;
  const int lrow = lane & 15;
  const int koff = (lane >> 4) * 8;

  f32x4 acc[2][8];
#pragma unroll
  for (int rt = 0; rt < 2; ++rt)
#pragma unroll
    for (int ct = 0; ct < 8; ++ct)
      acc[rt][ct] = (f32x4){0.f, 0.f, 0.f, 0.f};

  int r0 = rbase + lrow;      if (r0 > nN - 1) r0 = nN - 1;
  int r1 = rbase + 16 + lrow; if (r1 > nN - 1) r1 = nN - 1;

#pragma unroll
  for (int s = 0; s < 2; ++s) {
    const float* A = s ? A1 : A0;
    const float* a0p = A + (size_t)r0 * DIM;
    const float* a1p = A + (size_t)r1 * DIM;
#pragma unroll
    for (int ks = 0; ks < 4; ++ks) {
      int ka = ks * 32 + koff;
      int kw = s * 128 + ka;
      s16x8 ah0, al0, ah1, al1;
      split_frag(a0p + ka, ah0, al0);
      split_frag(a1p + ka, ah1, al1);
#pragma unroll
      for (int ct = 0; ct < 8; ++ct) {
        int c = ct * 16 + lrow;
        s16x8 wh = *reinterpret_cast<const s16x8*>(Wth + (size_t)c * 256 + kw);
        s16x8 wl = *reinterpret_cast<const s16x8*>(Wtl + (size_t)c * 256 + kw);
        acc[0][ct] = __builtin_amdgcn_mfma_f32_16x16x32_bf16(ah0, wh, acc[0][ct], 0, 0, 0);
        acc[0][ct] = __builtin_amdgcn_mfma_f32_16x16x32_bf16(ah0, wl, acc[0][ct], 0, 0, 0);
        acc[0][ct] = __builtin_amdgcn_mfma_f32_16x16x32_bf16(al0, wh, acc[0][ct], 0, 0, 0);
        acc[1][ct] = __builtin_amdgcn_mfma_f32_16x16x32_bf16(ah1, wh, acc[1][ct], 0, 0, 0);
        acc[1][ct] = __builtin_amdgcn_mfma_f32_16x16x32_bf16(ah1, wl, acc[1][ct], 0, 0, 0);
        acc[1][ct] = __builtin_amdgcn_mfma_f32_16x16x32_bf16(al1, wh, acc[1][ct], 0, 0, 0);
      }
    }
  }

#pragma unroll
  for (int ct = 0; ct < 8; ++ct) {
    int c = ct * 16 + lrow;
    float b = bias[c];
#pragma unroll
    for (int rt = 0; rt < 2; ++rt) {
      int rr = rbase + rt * 16 + (lane >> 4) * 4;
#pragma unroll
      for (int j = 0; j < 4; ++j) {
        int row = rr + j;
        if (row < nN) h[(size_t)row * DIM + c] = acc[rt][ct][j] + b;
      }
    }
  }
}

__global__ __launch_bounds__(256) void stats_kernel(const float* __restrict__ h,
                                                    float* __restrict__ sums, int nN) {
  __shared__ float s_s[256];
  __shared__ float s_q[256];
  int tid = threadIdx.x;
  int c = tid & 127;
  int rp = tid >> 7;
  float ls = 0.f, lq = 0.f;
  for (int r = blockIdx.x * 2 + rp; r < nN; r += gridDim.x * 2) {
    float v = h[(size_t)r * DIM + c];
    ls += v;
    lq += v * v;
  }
  s_s[tid] = ls;
  s_q[tid] = lq;
  __syncthreads();
  if (tid < 128) {
    atomicAdd(&sums[c], s_s[tid] + s_s[tid + 128]);
    atomicAdd(&sums[DIM + c], s_q[tid] + s_q[tid + 128]);
  }
}

__global__ __launch_bounds__(256) void bn_relu_kernel(const float* __restrict__ h,
    const float* __restrict__ sums, const float* __restrict__ gamma,
    const float* __restrict__ beta, float* __restrict__ xout, int nN) {
  int idx = blockIdx.x * 256 + threadIdx.x;
  int total = nN * (DIM / 4);
  if (idx >= total) return;
  int c = (idx & 31) * 4;
  float invN = 1.0f / (float)nN;
  float4 hv = reinterpret_cast<const float4*>(h)[idx];
  const float* hp = reinterpret_cast<const float*>(&hv);
  float4 o;
  float* op = reinterpret_cast<float*>(&o);
#pragma unroll
  for (int j = 0; j < 4; ++j) {
    float mu = sums[c + j] * invN;
    float var = sums[DIM + c + j] * invN - mu * mu;
    float sc = gamma[c + j] * rsqrtf(var + EPS);
    float sh = beta[c + j] - mu * sc;
    op[j] = fmaxf(hp[j] * sc + sh, 0.0f);
  }
  reinterpret_cast<float4*>(xout)[idx] = o;
}

// --- fused final BN+ReLU + segmented mean-pool ------------------------------
// Rows partitioned 32 per block; batch sorted so each slice has few runs.
#define POOL_ROWS 32
__global__ __launch_bounds__(256) void pool_fused_kernel(const float* __restrict__ h,
    const float* __restrict__ sums, const float* __restrict__ gamma,
    const float* __restrict__ beta, const int* __restrict__ batch,
    float* __restrict__ outsum, int nN) {
  int c = threadIdx.x & 127;
  int rp = threadIdx.x >> 7;
  int r0 = blockIdx.x * POOL_ROWS;
  float invN = 1.0f / (float)nN;
  float mu = sums[c] * invN;
  float var = sums[DIM + c] * invN - mu * mu;
  float sc = gamma[c] * rsqrtf(var + EPS);
  float sh = beta[c] - mu * sc;
  int rend = min(r0 + POOL_ROWS, nN);
  float acc = 0.f;
  int cur = -1;
  for (int r = r0 + rp; r < rend; r += 2) {
    int g = batch[r];
    float v = fmaxf(h[(size_t)r * DIM + c] * sc + sh, 0.0f);
    if (g != cur) {
      if (cur >= 0) atomicAdd(&outsum[(size_t)cur * DIM + c], acc);
      cur = g; acc = 0.f;
    }
    acc += v;
  }
  if (cur >= 0) atomicAdd(&outsum[(size_t)cur * DIM + c], acc);
}

__global__ __launch_bounds__(256) void pool_div_kernel(const float* __restrict__ outsum,
    const int* __restrict__ batch, float* __restrict__ out, int nN, int nG) {
  int idx = blockIdx.x * 256 + threadIdx.x;  // g*128 + c
  if (idx >= nG * DIM) return;
  int g = idx >> 7;
  int lo = lower_bound_i(batch, nN, g);
  int hi = lower_bound_i(batch, nN, g + 1);
  float cnt = fmaxf((float)(hi - lo), 1.0f);
  out[idx] = outsum[idx] / cnt;
}

extern "C" void kernel_launch(void* const* d_in, const int* in_sizes, int n_in,
                              void* d_out, int out_size, void* d_ws, size_t ws_size,
                              hipStream_t stream) {
  const float* x     = (const float*)d_in[0];
  const int*   ei    = (const int*)d_in[1];
  const int*   batch = (const int*)d_in[2];
  const float* W_l   = (const float*)d_in[3];
  const float* b_l   = (const float*)d_in[4];
  const float* W_r   = (const float*)d_in[5];
  const float* gamma = (const float*)d_in[6];
  const float* beta  = (const float*)d_in[7];
  float* out = (float*)d_out;

  const int N = in_sizes[2];
  const int E = in_sizes[1] / 2;
  const int G = out_size / DIM;
  const int L = in_sizes[3] / (DIM * DIM);

  const int* src  = ei;
  const int* dstE = ei + E;

  // workspace layout
  char* wsb = (char*)d_ws;
  float* agg    = (float*)wsb;  wsb += (size_t)N * DIM * sizeof(float);
  float* h      = (float*)wsb;  wsb += (size_t)N * DIM * sizeof(float);
  float* xb     = (float*)wsb;  wsb += (size_t)N * DIM * sizeof(float);
  float* sums   = (float*)wsb;  wsb += 2 * DIM * sizeof(float);
  float* outsum = (float*)wsb;  wsb += (size_t)G * DIM * sizeof(float);
  int* cnt    = (int*)wsb;      wsb += (size_t)N * sizeof(int);
  int* rowptr = (int*)wsb;      wsb += (size_t)(N + 1) * sizeof(int);
  int* cursor = (int*)wsb;      wsb += (size_t)N * sizeof(int);
  int* eidx   = (int*)wsb;      wsb += (size_t)E * sizeof(int);
  unsigned short* Wth = (unsigned short*)wsb; wsb += (size_t)DIM * 256 * sizeof(unsigned short);
  unsigned short* Wtl = (unsigned short*)wsb; wsb += (size_t)DIM * 256 * sizeof(unsigned short);

  // CSR build
  hipMemsetAsync(cnt, 0, (size_t)N * sizeof(int), stream);
  hipMemsetAsync(cursor, 0, (size_t)N * sizeof(int), stream);
  hist_kernel<<<(E + 255) / 256, 256, 0, stream>>>(dstE, cnt, E);
  scan_kernel<<<1, SCAN_T, 0, stream>>>(cnt, rowptr, N);
  fill_kernel<<<(E + 255) / 256, 256, 0, stream>>>(src, dstE, rowptr, cursor, eidx, E);

  const float* xin = x;
  for (int l = 0; l < L; ++l) {
    cvt_w_kernel<<<(DIM * 256 + 255) / 256, 256, 0, stream>>>(
        W_l + (size_t)l * DIM * DIM, W_r + (size_t)l * DIM * DIM, Wth, Wtl);
    gather_kernel<<<(N * 32 + 255) / 256, 256, 0, stream>>>(xin, rowptr, eidx, agg, N);
    gemm_mfma_kernel<<<(N + 127) / 128, 256, 0, stream>>>(agg, xin, Wth, Wtl,
        b_l + (size_t)l * DIM, h, N);
    hipMemsetAsync(sums, 0, 2 * DIM * sizeof(float), stream);
    stats_kernel<<<240, 256, 0, stream>>>(h, sums, N);
    if (l < L - 1) {
      bn_relu_kernel<<<(N * (DIM / 4) + 255) / 256, 256, 0, stream>>>(
          h, sums, gamma + (size_t)l * DIM, beta + (size_t)l * DIM, xb, N);
      xin = xb;
    } else {
      hipMemsetAsync(outsum, 0, (size_t)G * DIM * sizeof(float), stream);
      pool_fused_kernel<<<(N + POOL_ROWS - 1) / POOL_ROWS, 256, 0, stream>>>(
          h, sums, gamma + (size_t)l * DIM, beta + (size_t)l * DIM, batch, outsum, N);
      pool_div_kernel<<<(G * DIM + 255) / 256, 256, 0, stream>>>(outsum, batch, out, N, G);
    }
  }
}

// Round 5
// 362.490 us; speedup vs baseline: 7.0257x; 1.1798x over previous
//
#include <hip/hip_runtime.h>

#define DIM 128
#define EPS 1e-5f
#define SCAN_TILE 2048  // 256 threads x 8 elements

typedef short s16x8 __attribute__((ext_vector_type(8)));
typedef float f32x4 __attribute__((ext_vector_type(4)));

__device__ __forceinline__ int lower_bound_i(const int* __restrict__ a, int n, int key) {
  int lo = 0, hi = n;
  while (lo < hi) {
    int mid = (lo + hi) >> 1;
    if (a[mid] < key) lo = mid + 1; else hi = mid;
  }
  return lo;
}

__device__ __forceinline__ unsigned rne_bf16(float f) {
  unsigned u = __builtin_bit_cast(unsigned, f);
  return (u + 0x7fffu + ((u >> 16) & 1u)) >> 16;
}
__device__ __forceinline__ float bf16_hi_to_f32(unsigned h) {
  return __builtin_bit_cast(float, h << 16);
}

__device__ __forceinline__ void split_frag(const float* __restrict__ base,
                                           s16x8& hi, s16x8& lo) {
  float4 f0 = *reinterpret_cast<const float4*>(base);
  float4 f1 = *reinterpret_cast<const float4*>(base + 4);
  float v[8] = {f0.x, f0.y, f0.z, f0.w, f1.x, f1.y, f1.z, f1.w};
#pragma unroll
  for (int j = 0; j < 8; ++j) {
    unsigned h = rne_bf16(v[j]);
    float r = v[j] - bf16_hi_to_f32(h);
    hi[j] = (short)h;
    lo[j] = (short)rne_bf16(r);
  }
}

// --- CSR build -------------------------------------------------------------
__global__ __launch_bounds__(256) void hist_kernel(const int* __restrict__ dst,
                                                   int* __restrict__ cnt, int nE) {
  int i = blockIdx.x * 256 + threadIdx.x;
  if (i < nE) atomicAdd(&cnt[dst[i]], 1);
}

// Phase 1: per-block tile sums.
__global__ __launch_bounds__(256) void scan1_kernel(const int* __restrict__ cnt,
                                                    int* __restrict__ bsum, int nN) {
  __shared__ int s[256];
  int t = threadIdx.x;
  int base = blockIdx.x * SCAN_TILE + t * 8;
  int sum = 0;
#pragma unroll
  for (int j = 0; j < 8; ++j) {
    int i = base + j;
    if (i < nN) sum += cnt[i];
  }
  s[t] = sum;
  __syncthreads();
  for (int off = 128; off > 0; off >>= 1) {
    if (t < off) s[t] += s[t + off];
    __syncthreads();
  }
  if (t == 0) bsum[blockIdx.x] = s[0];
}

// Phase 2: serial scan of block sums (nB ~ 25) + write rowptr[nN].
__global__ __launch_bounds__(64) void scan2_kernel(int* __restrict__ bsum,
                                                   int* __restrict__ rowptr,
                                                   int nB, int nN) {
  if (threadIdx.x == 0) {
    int run = 0;
    for (int b = 0; b < nB; ++b) {
      int v = bsum[b];
      bsum[b] = run;
      run += v;
    }
    rowptr[nN] = run;
  }
}

// Phase 3: local exclusive scan within each tile + block offset.
__global__ __launch_bounds__(256) void scan3_kernel(const int* __restrict__ cnt,
                                                    const int* __restrict__ bsum,
                                                    int* __restrict__ rowptr, int nN) {
  __shared__ int s[256];
  int t = threadIdx.x;
  int base = blockIdx.x * SCAN_TILE + t * 8;
  int v[8];
  int tsum = 0;
#pragma unroll
  for (int j = 0; j < 8; ++j) {
    int i = base + j;
    v[j] = (i < nN) ? cnt[i] : 0;
    tsum += v[j];
  }
  s[t] = tsum;
  __syncthreads();
  for (int off = 1; off < 256; off <<= 1) {
    int u = (t >= off) ? s[t - off] : 0;
    __syncthreads();
    s[t] += u;
    __syncthreads();
  }
  int run = bsum[blockIdx.x] + ((t > 0) ? s[t - 1] : 0);
#pragma unroll
  for (int j = 0; j < 8; ++j) {
    int i = base + j;
    if (i < nN) rowptr[i] = run;
    run += v[j];
  }
}

__global__ __launch_bounds__(256) void fill_kernel(const int* __restrict__ src,
    const int* __restrict__ dst, const int* __restrict__ rowptr,
    int* __restrict__ cursor, int* __restrict__ eidx, int nE) {
  int e = blockIdx.x * 256 + threadIdx.x;
  if (e < nE) {
    int d = dst[e];
    int p = atomicAdd(&cursor[d], 1);
    eidx[rowptr[d] + p] = src[e];
  }
}

// --- mean-aggregate via gather: 32 threads per dst node --------------------
__global__ __launch_bounds__(256) void gather_kernel(const float* __restrict__ x,
    const int* __restrict__ rowptr, const int* __restrict__ eidx,
    float* __restrict__ agg, int nN) {
  int grp = (blockIdx.x * 256 + threadIdx.x) >> 5;
  int j = threadIdx.x & 31;
  if (grp >= nN) return;
  int lo = rowptr[grp], hi = rowptr[grp + 1];
  float4 acc = make_float4(0.f, 0.f, 0.f, 0.f);
  int i = lo;
  for (; i + 1 < hi; i += 2) {
    int s0 = eidx[i], s1 = eidx[i + 1];
    float4 v0 = reinterpret_cast<const float4*>(x)[(size_t)s0 * 32 + j];
    float4 v1 = reinterpret_cast<const float4*>(x)[(size_t)s1 * 32 + j];
    acc.x += v0.x; acc.y += v0.y; acc.z += v0.z; acc.w += v0.w;
    acc.x += v1.x; acc.y += v1.y; acc.z += v1.z; acc.w += v1.w;
  }
  if (i < hi) {
    int s0 = eidx[i];
    float4 v0 = reinterpret_cast<const float4*>(x)[(size_t)s0 * 32 + j];
    acc.x += v0.x; acc.y += v0.y; acc.z += v0.z; acc.w += v0.w;
  }
  float invd = 1.0f / fmaxf((float)(hi - lo), 1.0f);
  acc.x *= invd; acc.y *= invd; acc.z *= invd; acc.w *= invd;
  reinterpret_cast<float4*>(agg)[(size_t)grp * 32 + j] = acc;
}

// --- W prep ---------------------------------------------------------------
__global__ __launch_bounds__(256) void cvt_w_kernel(const float* __restrict__ Wl,
    const float* __restrict__ Wr, unsigned short* __restrict__ Wth,
    unsigned short* __restrict__ Wtl) {
  int idx = blockIdx.x * 256 + threadIdx.x;  // c*256 + k
  if (idx >= DIM * 256) return;
  int c = idx >> 8, k = idx & 255;
  float v = (k < DIM) ? Wl[(size_t)k * DIM + c] : Wr[(size_t)(k - DIM) * DIM + c];
  unsigned h = rne_bf16(v);
  float r = v - bf16_hi_to_f32(h);
  Wth[idx] = (unsigned short)h;
  Wtl[idx] = (unsigned short)rne_bf16(r);
}

// --- fused dual-GEMM via bf16 split-precision MFMA --------------------------
__global__ __launch_bounds__(256) void gemm_mfma_kernel(
    const float* __restrict__ A0, const float* __restrict__ A1,
    const unsigned short* __restrict__ Wth, const unsigned short* __restrict__ Wtl,
    const float* __restrict__ bias, float* __restrict__ h, int nN) {
  const int lane = threadIdx.x & 63;
  const int wave = threadIdx.x >> 6;
  const int rbase = blockIdx.x * 128 + wave * 32;
  const int lrow = lane & 15;
  const int koff = (lane >> 4) * 8;

  f32x4 acc[2][8];
#pragma unroll
  for (int rt = 0; rt < 2; ++rt)
#pragma unroll
    for (int ct = 0; ct < 8; ++ct)
      acc[rt][ct] = (f32x4){0.f, 0.f, 0.f, 0.f};

  int r0 = rbase + lrow;      if (r0 > nN - 1) r0 = nN - 1;
  int r1 = rbase + 16 + lrow; if (r1 > nN - 1) r1 = nN - 1;

#pragma unroll
  for (int s = 0; s < 2; ++s) {
    const float* A = s ? A1 : A0;
    const float* a0p = A + (size_t)r0 * DIM;
    const float* a1p = A + (size_t)r1 * DIM;
#pragma unroll
    for (int ks = 0; ks < 4; ++ks) {
      int ka = ks * 32 + koff;
      int kw = s * 128 + ka;
      s16x8 ah0, al0, ah1, al1;
      split_frag(a0p + ka, ah0, al0);
      split_frag(a1p + ka, ah1, al1);
#pragma unroll
      for (int ct = 0; ct < 8; ++ct) {
        int c = ct * 16 + lrow;
        s16x8 wh = *reinterpret_cast<const s16x8*>(Wth + (size_t)c * 256 + kw);
        s16x8 wl = *reinterpret_cast<const s16x8*>(Wtl + (size_t)c * 256 + kw);
        acc[0][ct] = __builtin_amdgcn_mfma_f32_16x16x32_bf16(ah0, wh, acc[0][ct], 0, 0, 0);
        acc[0][ct] = __builtin_amdgcn_mfma_f32_16x16x32_bf16(ah0, wl, acc[0][ct], 0, 0, 0);
        acc[0][ct] = __builtin_amdgcn_mfma_f32_16x16x32_bf16(al0, wh, acc[0][ct], 0, 0, 0);
        acc[1][ct] = __builtin_amdgcn_mfma_f32_16x16x32_bf16(ah1, wh, acc[1][ct], 0, 0, 0);
        acc[1][ct] = __builtin_amdgcn_mfma_f32_16x16x32_bf16(ah1, wl, acc[1][ct], 0, 0, 0);
        acc[1][ct] = __builtin_amdgcn_mfma_f32_16x16x32_bf16(al1, wh, acc[1][ct], 0, 0, 0);
      }
    }
  }

#pragma unroll
  for (int ct = 0; ct < 8; ++ct) {
    int c = ct * 16 + lrow;
    float b = bias[c];
#pragma unroll
    for (int rt = 0; rt < 2; ++rt) {
      int rr = rbase + rt * 16 + (lane >> 4) * 4;
#pragma unroll
      for (int j = 0; j < 4; ++j) {
        int row = rr + j;
        if (row < nN) h[(size_t)row * DIM + c] = acc[rt][ct][j] + b;
      }
    }
  }
}

__global__ __launch_bounds__(256) void stats_kernel(const float* __restrict__ h,
                                                    float* __restrict__ sums, int nN) {
  __shared__ float s_s[256];
  __shared__ float s_q[256];
  int tid = threadIdx.x;
  int c = tid & 127;
  int rp = tid >> 7;
  float ls = 0.f, lq = 0.f;
  for (int r = blockIdx.x * 2 + rp; r < nN; r += gridDim.x * 2) {
    float v = h[(size_t)r * DIM + c];
    ls += v;
    lq += v * v;
  }
  s_s[tid] = ls;
  s_q[tid] = lq;
  __syncthreads();
  if (tid < 128) {
    atomicAdd(&sums[c], s_s[tid] + s_s[tid + 128]);
    atomicAdd(&sums[DIM + c], s_q[tid] + s_q[tid + 128]);
  }
}

__global__ __launch_bounds__(256) void bn_relu_kernel(const float* __restrict__ h,
    const float* __restrict__ sums, const float* __restrict__ gamma,
    const float* __restrict__ beta, float* __restrict__ xout, int nN) {
  int idx = blockIdx.x * 256 + threadIdx.x;
  int total = nN * (DIM / 4);
  if (idx >= total) return;
  int c = (idx & 31) * 4;
  float invN = 1.0f / (float)nN;
  float4 hv = reinterpret_cast<const float4*>(h)[idx];
  const float* hp = reinterpret_cast<const float*>(&hv);
  float4 o;
  float* op = reinterpret_cast<float*>(&o);
#pragma unroll
  for (int j = 0; j < 4; ++j) {
    float mu = sums[c + j] * invN;
    float var = sums[DIM + c + j] * invN - mu * mu;
    float sc = gamma[c + j] * rsqrtf(var + EPS);
    float sh = beta[c + j] - mu * sc;
    op[j] = fmaxf(hp[j] * sc + sh, 0.0f);
  }
  reinterpret_cast<float4*>(xout)[idx] = o;
}

// --- fused final BN+ReLU + segmented mean-pool ------------------------------
#define POOL_ROWS 32
__global__ __launch_bounds__(256) void pool_fused_kernel(const float* __restrict__ h,
    const float* __restrict__ sums, const float* __restrict__ gamma,
    const float* __restrict__ beta, const int* __restrict__ batch,
    float* __restrict__ outsum, int nN) {
  int c = threadIdx.x & 127;
  int rp = threadIdx.x >> 7;
  int r0 = blockIdx.x * POOL_ROWS;
  float invN = 1.0f / (float)nN;
  float mu = sums[c] * invN;
  float var = sums[DIM + c] * invN - mu * mu;
  float sc = gamma[c] * rsqrtf(var + EPS);
  float sh = beta[c] - mu * sc;
  int rend = min(r0 + POOL_ROWS, nN);
  float acc = 0.f;
  int cur = -1;
  for (int r = r0 + rp; r < rend; r += 2) {
    int g = batch[r];
    float v = fmaxf(h[(size_t)r * DIM + c] * sc + sh, 0.0f);
    if (g != cur) {
      if (cur >= 0) atomicAdd(&outsum[(size_t)cur * DIM + c], acc);
      cur = g; acc = 0.f;
    }
    acc += v;
  }
  if (cur >= 0) atomicAdd(&outsum[(size_t)cur * DIM + c], acc);
}

__global__ __launch_bounds__(256) void pool_div_kernel(const float* __restrict__ outsum,
    const int* __restrict__ batch, float* __restrict__ out, int nN, int nG) {
  int idx = blockIdx.x * 256 + threadIdx.x;  // g*128 + c
  if (idx >= nG * DIM) return;
  int g = idx >> 7;
  int lo = lower_bound_i(batch, nN, g);
  int hi = lower_bound_i(batch, nN, g + 1);
  float cnt = fmaxf((float)(hi - lo), 1.0f);
  out[idx] = outsum[idx] / cnt;
}

extern "C" void kernel_launch(void* const* d_in, const int* in_sizes, int n_in,
                              void* d_out, int out_size, void* d_ws, size_t ws_size,
                              hipStream_t stream) {
  const float* x     = (const float*)d_in[0];
  const int*   ei    = (const int*)d_in[1];
  const int*   batch = (const int*)d_in[2];
  const float* W_l   = (const float*)d_in[3];
  const float* b_l   = (const float*)d_in[4];
  const float* W_r   = (const float*)d_in[5];
  const float* gamma = (const float*)d_in[6];
  const float* beta  = (const float*)d_in[7];
  float* out = (float*)d_out;

  const int N = in_sizes[2];
  const int E = in_sizes[1] / 2;
  const int G = out_size / DIM;
  const int L = in_sizes[3] / (DIM * DIM);

  const int* src  = ei;
  const int* dstE = ei + E;

  const int nB = (N + SCAN_TILE - 1) / SCAN_TILE;

  // workspace layout
  char* wsb = (char*)d_ws;
  float* agg    = (float*)wsb;  wsb += (size_t)N * DIM * sizeof(float);
  float* h      = (float*)wsb;  wsb += (size_t)N * DIM * sizeof(float);
  float* xb     = (float*)wsb;  wsb += (size_t)N * DIM * sizeof(float);
  float* sums   = (float*)wsb;  wsb += 2 * DIM * sizeof(float);
  float* outsum = (float*)wsb;  wsb += (size_t)G * DIM * sizeof(float);
  int* cnt    = (int*)wsb;      wsb += (size_t)N * sizeof(int);
  int* rowptr = (int*)wsb;      wsb += (size_t)(N + 1) * sizeof(int);
  int* cursor = (int*)wsb;      wsb += (size_t)N * sizeof(int);
  int* bsum   = (int*)wsb;      wsb += (size_t)nB * sizeof(int);
  int* eidx   = (int*)wsb;      wsb += (size_t)E * sizeof(int);
  unsigned short* Wth = (unsigned short*)wsb; wsb += (size_t)DIM * 256 * sizeof(unsigned short);
  unsigned short* Wtl = (unsigned short*)wsb; wsb += (size_t)DIM * 256 * sizeof(unsigned short);

  // CSR build
  hipMemsetAsync(cnt, 0, (size_t)N * sizeof(int), stream);
  hipMemsetAsync(cursor, 0, (size_t)N * sizeof(int), stream);
  hist_kernel<<<(E + 255) / 256, 256, 0, stream>>>(dstE, cnt, E);
  scan1_kernel<<<nB, 256, 0, stream>>>(cnt, bsum, N);
  scan2_kernel<<<1, 64, 0, stream>>>(bsum, rowptr, nB, N);
  scan3_kernel<<<nB, 256, 0, stream>>>(cnt, bsum, rowptr, N);
  fill_kernel<<<(E + 255) / 256, 256, 0, stream>>>(src, dstE, rowptr, cursor, eidx, E);

  const float* xin = x;
  for (int l = 0; l < L; ++l) {
    cvt_w_kernel<<<(DIM * 256 + 255) / 256, 256, 0, stream>>>(
        W_l + (size_t)l * DIM * DIM, W_r + (size_t)l * DIM * DIM, Wth, Wtl);
    gather_kernel<<<(N * 32 + 255) / 256, 256, 0, stream>>>(xin, rowptr, eidx, agg, N);
    gemm_mfma_kernel<<<(N + 127) / 128, 256, 0, stream>>>(agg, xin, Wth, Wtl,
        b_l + (size_t)l * DIM, h, N);
    hipMemsetAsync(sums, 0, 2 * DIM * sizeof(float), stream);
    stats_kernel<<<240, 256, 0, stream>>>(h, sums, N);
    if (l < L - 1) {
      bn_relu_kernel<<<(N * (DIM / 4) + 255) / 256, 256, 0, stream>>>(
          h, sums, gamma + (size_t)l * DIM, beta + (size_t)l * DIM, xb, N);
      xin = xb;
    } else {
      hipMemsetAsync(outsum, 0, (size_t)G * DIM * sizeof(float), stream);
      pool_fused_kernel<<<(N + POOL_ROWS - 1) / POOL_ROWS, 256, 0, stream>>>(
          h, sums, gamma + (size_t)l * DIM, beta + (size_t)l * DIM, batch, outsum, N);
      pool_div_kernel<<<(G * DIM + 255) / 256, 256, 0, stream>>>(outsum, batch, out, N, G);
    }
  }
}